// Round 15
// baseline (283.341 us; speedup 1.0000x reference)
//
#include <hip/hip_runtime.h>
#include <hip/hip_bf16.h>
#include <hip/hip_fp16.h>
#include <math.h>

// Edge_Encoder_Residual: 2-layer GATv2 on line-graph + time-MLP + decoder.
// Round 15: pipeline cleanup. (1) k_scan fused into k_histc (last-block
// scan, device-scope atomic reads for cross-XCD coherence); (2) k_refine
// now exact per-dst counting sort -> global rowptr[N+1] + plain srcs;
// (3) gat3's per-block counting sort becomes a straight LDS copy (2
// barriers + 1024 LDS atomics removed per block). Edge loop + fused
// layer-1-precompute epilogue (r14) unchanged.

#define BLK 256
#define BDST 32            // dsts per fine bucket
#define CDST 256           // dsts per coarse bucket
#define CHUNK 4096         // edges per k_part block
#define FCAP 1024          // LDS tag capacity per bucket (mean 512, +22 sigma)
#define NBC_MAX 512

typedef _Float16 half4v __attribute__((ext_vector_type(4)));
typedef _Float16 half2v __attribute__((ext_vector_type(2)));

#if __has_builtin(__builtin_amdgcn_fdot2)
#define FDOT2(a, b, c) __builtin_amdgcn_fdot2((a), (b), (c), false)
#else
__device__ __forceinline__ float fdot2_fallback(half2v a, half2v b, float c) {
    return c + (float)a.x * (float)b.x + (float)a.y * (float)b.y;
}
#define FDOT2(a, b, c) fdot2_fallback((a), (b), (c))
#endif

__device__ __forceinline__ float relu(float x) { return x > 0.f ? x : 0.f; }

// packed logit partial: sum_c leaky(h[c]+xr[c])*att[c] over this lane's 4 ch
__device__ __forceinline__ float edot(half4v h, half2v xlo, half2v xhi,
                                      half2v alo, half2v ahi, half2v c02) {
    half2v lo = half2v{h.x, h.y} + xlo;
    half2v hi = half2v{h.z, h.w} + xhi;
    lo = __builtin_elementwise_max(lo, lo * c02);
    hi = __builtin_elementwise_max(hi, hi * c02);
    return FDOT2(lo, alo, FDOT2(hi, ahi, 0.f));
}

// ---------- tiny: time-MLP + decoder collapse + counters zero + W1 fp16 ------
__global__ void k_tiny(const int* __restrict__ t,
                       const float* __restrict__ Wt0, const float* __restrict__ bt0,
                       const float* __restrict__ Wt1, const float* __restrict__ bt1,
                       const float* __restrict__ Wfd, const float* __restrict__ bfd,
                       const float* __restrict__ Wcls, const float* __restrict__ bcls,
                       const float* __restrict__ Wl1, const float* __restrict__ Wr1,
                       const float* __restrict__ Wres1,
                       float* __restrict__ wcomb,   // [96][2]
                       float* __restrict__ bfinal,  // [2]
                       half4v* __restrict__ w16,    // [3][16][64] half4 (k-quads)
                       int* __restrict__ ccnt, int* __restrict__ donecnt, int NBC)
{
    __shared__ float temb[16];
    int tid = threadIdx.x;
    for (int i = tid; i < NBC; i += BLK) ccnt[i] = 0;
    if (tid == 0) *donecnt = 0;
    for (int idx = tid; idx < 3 * 1024; idx += BLK) {
        int m = idx >> 10, rem = idx & 1023;
        int k4 = rem >> 6, c = rem & 63;
        const float* W = (m == 0) ? Wl1 : (m == 1) ? Wr1 : Wres1;
        half4v v;
        v.x = (_Float16)W[(4 * k4 + 0) * 64 + c];
        v.y = (_Float16)W[(4 * k4 + 1) * 64 + c];
        v.z = (_Float16)W[(4 * k4 + 2) * 64 + c];
        v.w = (_Float16)W[(4 * k4 + 3) * 64 + c];
        w16[idx] = v;
    }
    if (tid == 0) {
        float tf = (float)t[0];
        float e0[16], v1[16];
        const float cexp = -logf(10000.f) / 7.f;
        for (int j = 0; j < 8; ++j) {
            float ang = tf * expf((float)j * cexp);
            e0[j] = sinf(ang);
            e0[8 + j] = cosf(ang);
        }
        for (int i = 0; i < 16; ++i) {
            float a = bt0[i];
            for (int j = 0; j < 16; ++j) a += e0[j] * Wt0[j * 16 + i];
            v1[i] = a / (1.f + expf(-a));
        }
        for (int i = 0; i < 16; ++i) {
            float a = bt1[i];
            for (int j = 0; j < 16; ++j) a += v1[j] * Wt1[j * 16 + i];
            temb[i] = a / (1.f + expf(-a));
        }
    }
    __syncthreads();
    if (tid < 192) {
        int i = tid >> 1, k = tid & 1;
        float a = 0.f;
        for (int j = 0; j < 32; ++j) a += Wfd[i * 32 + j] * Wcls[j * 2 + k];
        wcomb[tid] = a;
    }
    __syncthreads();
    if (tid < 2) {
        float a = bcls[tid];
        for (int j = 0; j < 32; ++j) a += bfd[j] * Wcls[j * 2 + tid];
        for (int d = 0; d < 16; ++d) a += temb[d] * wcomb[(64 + d) * 2 + tid];
        bfinal[tid] = a;
    }
}

// ---------- histc + fused last-block scan ----------
__global__ void k_histc(const int* __restrict__ ei, int E, int NBC,
                        int* __restrict__ ccnt, int* __restrict__ donecnt,
                        int* __restrict__ cbase, int* __restrict__ ccur,
                        int nblocks)
{
    __shared__ int h[NBC_MAX];
    __shared__ int amlast;
    int tid = threadIdx.x;
    for (int i = tid; i < NBC; i += BLK) h[i] = 0;
    __syncthreads();
    int e0 = blockIdx.x * CHUNK;
    #pragma unroll
    for (int k = 0; k < CHUNK / BLK; ++k) {
        int e = e0 + tid + k * BLK;
        if (e < E) atomicAdd(&h[ei[E + e] >> 8], 1);
    }
    __syncthreads();
    for (int i = tid; i < NBC; i += BLK) {
        int v = h[i];
        if (v) atomicAdd(&ccnt[i], v);   // fire-and-forget -> pipelines
    }
    // last-block scan
    __threadfence();
    if (tid == 0) amlast = (atomicAdd(donecnt, 1) == nblocks - 1) ? 1 : 0;
    __syncthreads();
    if (amlast) {
        for (int i = tid; i < NBC; i += BLK)
            h[i] = atomicAdd(&ccnt[i], 0);   // device-scope coherent read
        __syncthreads();
        if (tid == 0) {
            int acc = 0;
            for (int i = 0; i < NBC; ++i) { cbase[i] = acc; acc += h[i]; }
            cbase[NBC] = acc;
        }
        __syncthreads();
        for (int i = tid; i < NBC; i += BLK) ccur[i] = cbase[i];
    }
}

__global__ void k_part(const int* __restrict__ ei, int E, int NBC,
                       int* __restrict__ ccur, int* __restrict__ part)
{
    __shared__ int h[NBC_MAX];
    __shared__ int gb[NBC_MAX];
    int tid = threadIdx.x;
    int e0 = blockIdx.x * CHUNK;
    for (int i = tid; i < NBC; i += BLK) h[i] = 0;
    __syncthreads();
    int sv[CHUNK / BLK], dv[CHUNK / BLK];
    #pragma unroll
    for (int k = 0; k < CHUNK / BLK; ++k) {
        int e = e0 + tid + k * BLK;
        if (e < E) {
            sv[k] = ei[e];
            dv[k] = ei[E + e];
            atomicAdd(&h[dv[k] >> 8], 1);
        } else dv[k] = -1;
    }
    __syncthreads();
    for (int i = tid; i < NBC; i += BLK) {
        int v = h[i];
        gb[i] = v ? atomicAdd(&ccur[i], v) : 0;   // block-agg returning atomics
    }
    __syncthreads();
    for (int i = tid; i < NBC; i += BLK) h[i] = gb[i];
    __syncthreads();
    #pragma unroll
    for (int k = 0; k < CHUNK / BLK; ++k) {
        if (dv[k] >= 0) {
            int p = atomicAdd(&h[dv[k] >> 8], 1);   // LDS atomic
            part[p] = (sv[k] << 8) | (dv[k] & 255);
        }
    }
}

// exact per-dst counting sort within each coarse segment -> rowptr + srcs
__global__ void k_refine(const int* __restrict__ cbase, const int* __restrict__ part,
                         int N, int* __restrict__ rowptr, int* __restrict__ srcs)
{
    __shared__ int fcnt[CDST];
    __shared__ int fcur[CDST];
    int b = blockIdx.x, tid = threadIdx.x;
    int beg = cbase[b], end = cbase[b + 1];
    fcnt[tid] = 0;                       // BLK == CDST == 256
    __syncthreads();
    for (int k = beg + tid; k < end; k += BLK)
        atomicAdd(&fcnt[part[k] & 255], 1);
    __syncthreads();
    if (tid == 0) {
        int acc = beg;
        #pragma unroll 8
        for (int i = 0; i < CDST; ++i) {
            fcur[i] = acc;
            int nd = b * CDST + i;
            if (nd < N) rowptr[nd] = acc;
            acc += fcnt[i];
        }
        if (b == gridDim.x - 1) rowptr[N] = acc;   // == E
    }
    __syncthreads();
    for (int k = beg + tid; k < end; k += BLK) {
        int tg = part[k];
        int p = atomicAdd(&fcur[tg & 255], 1);
        srcs[p] = tg >> 8;
    }
}

// ---------- layer 0 precompute: xl, xr, res — all fp16, 4 nodes/wave ----------
__global__ void k_pre0f(const float* __restrict__ x,
                        const float* __restrict__ Wl, const float* __restrict__ bl,
                        const float* __restrict__ Wr, const float* __restrict__ br,
                        const float* __restrict__ Wres, const float* __restrict__ bres,
                        _Float16* __restrict__ xlh, _Float16* __restrict__ xr16,
                        _Float16* __restrict__ res16, int N)
{
    int wid = (int)(((long long)blockIdx.x * BLK + threadIdx.x) >> 6);
    int lane = threadIdx.x & 63;
    int g = lane >> 4, q = lane & 15;
    int n = wid * 4 + g;
    bool valid = n < N;
    int nn = valid ? n : N - 1;
    float xv = x[(size_t)nn * 16 + q];
    int c0 = q * 4;
    float4 accl = *(const float4*)(bl + c0);
    float4 accr = *(const float4*)(br + c0);
    float4 accs = *(const float4*)(bres + c0);
    #pragma unroll
    for (int k = 0; k < 16; ++k) {
        float xk = __shfl(xv, (g << 4) | k, 64);
        float4 wl = *(const float4*)(Wl + k * 64 + c0);
        float4 wr = *(const float4*)(Wr + k * 64 + c0);
        float4 wsv = *(const float4*)(Wres + k * 64 + c0);
        accl.x = fmaf(xk, wl.x, accl.x);
        accl.y = fmaf(xk, wl.y, accl.y);
        accl.z = fmaf(xk, wl.z, accl.z);
        accl.w = fmaf(xk, wl.w, accl.w);
        accr.x = fmaf(xk, wr.x, accr.x);
        accr.y = fmaf(xk, wr.y, accr.y);
        accr.z = fmaf(xk, wr.z, accr.z);
        accr.w = fmaf(xk, wr.w, accr.w);
        accs.x = fmaf(xk, wsv.x, accs.x);
        accs.y = fmaf(xk, wsv.y, accs.y);
        accs.z = fmaf(xk, wsv.z, accs.z);
        accs.w = fmaf(xk, wsv.w, accs.w);
    }
    if (valid) {
        size_t base = (size_t)n * 64 + c0;
        half4v hl, hr, hs;
        hl.x = (_Float16)accl.x; hl.y = (_Float16)accl.y;
        hl.z = (_Float16)accl.z; hl.w = (_Float16)accl.w;
        hr.x = (_Float16)accr.x; hr.y = (_Float16)accr.y;
        hr.z = (_Float16)accr.z; hr.w = (_Float16)accr.w;
        hs.x = (_Float16)relu(accs.x); hs.y = (_Float16)relu(accs.y);
        hs.z = (_Float16)relu(accs.z); hs.w = (_Float16)relu(accs.w);
        *(half4v*)(xlh + base) = hl;
        *(half4v*)(xr16 + base) = hr;
        *(half4v*)(res16 + base) = hs;
    }
}

// ---------- fused GATv2 (+ layer-1 precompute GEMM for LAYER==0) ----------
template <int LAYER>
__global__ void k_gat3(const int* __restrict__ rowptr,
                       const int* __restrict__ srcs,
                       const _Float16* __restrict__ xlh, const _Float16* __restrict__ xr16,
                       const float* __restrict__ att, const float* __restrict__ bias,
                       const _Float16* __restrict__ res16,
                       const half4v* __restrict__ w16, const float* __restrict__ bres1,
                       _Float16* __restrict__ xlh_out, _Float16* __restrict__ xr_out,
                       _Float16* __restrict__ res_out,
                       const float* __restrict__ cond, const float* __restrict__ wcomb,
                       const float* __restrict__ bfinal, float* __restrict__ out,
                       int N)
{
    __shared__ int rp[BDST + 1];
    __shared__ int sidx[BDST];
    __shared__ int tags[FCAP];
    __shared__ half4v h4[LAYER == 0 ? 32 : 1][16];   // h stash (4KB, L0 only)

    int b = blockIdx.x;
    int tid = threadIdx.x;
    int nb = b * BDST;

    if (tid < BDST + 1) {
        int nd = nb + tid; if (nd > N) nd = N;
        rp[tid] = rowptr[nd];
    }
    __syncthreads();
    int beg = rp[0];
    int nE = rp[BDST] - beg; if (nE > FCAP) nE = FCAP;
    for (int k = tid; k < nE; k += BLK) tags[k] = srcs[beg + k];   // already sorted
    // degree-rank: sidx[rank] = dlow, descending degree (ties by index)
    if (tid < BDST) {
        int di = rp[tid + 1] - rp[tid];
        int r = 0;
        #pragma unroll
        for (int j = 0; j < BDST; ++j) {
            int dj = rp[j + 1] - rp[j];
            r += (dj > di) || (dj == di && j < tid);
        }
        sidx[r] = tid;
    }
    __syncthreads();

    int lane = tid & 63, w = tid >> 6;
    int g = lane >> 4, q = lane & 15;
    int c0 = q * 4;
    float4 a4f = *(const float4*)(att + c0);
    const half2v c02 = { (_Float16)0.2f, (_Float16)0.2f };
    half2v alo = { (_Float16)a4f.x, (_Float16)a4f.y };
    half2v ahi = { (_Float16)a4f.z, (_Float16)a4f.w };

    #pragma unroll
    for (int rep = 0; rep < 2; ++rep) {
        int dlow = sidx[w * 8 + rep * 4 + g];   // similar-degree group
        int node = nb + dlow;
        bool nvalid = node < N;
        int n = nvalid ? node : 0;

        half4v xrh = *(const half4v*)(xr16 + (size_t)n * 64 + c0);
        half2v xlo = { xrh.x, xrh.y }, xhi = { xrh.z, xrh.w };

        half4v hsv = *(const half4v*)(xlh + (size_t)n * 64 + c0);
        float lv = edot(hsv, xlo, xhi, alo, ahi, c02);
        lv += __shfl_xor(lv, 1, 8);
        lv += __shfl_xor(lv, 2, 8);
        lv += __shfl_xor(lv, 4, 8);

        float m = lv, den = 1.f;
        float ac0 = (float)hsv.x, ac1 = (float)hsv.y;
        float ac2 = (float)hsv.z, ac3 = (float)hsv.w;

        int deg = nvalid ? (rp[dlow + 1] - rp[dlow]) : 0;
        int base = nvalid ? (rp[dlow] - beg) : 0;     // relative into tags
        if (base + deg > nE) deg = (base < nE) ? nE - base : 0;   // FCAP guard

        int t1 = max(deg, __shfl_xor(deg, 16, 64));
        int wavemax = max(t1, __shfl_xor(t1, 32, 64));

        // 4-deep prefetch
        int i1 = (0 < deg) ? tags[base + 0] : n;
        int i2 = (1 < deg) ? tags[base + 1] : n;
        int i3 = (2 < deg) ? tags[base + 2] : n;
        int i4 = (3 < deg) ? tags[base + 3] : n;
        half4v p1 = *(const half4v*)(xlh + (size_t)i1 * 64 + c0);
        half4v p2 = *(const half4v*)(xlh + (size_t)i2 * 64 + c0);
        half4v p3 = *(const half4v*)(xlh + (size_t)i3 * 64 + c0);
        half4v p4 = *(const half4v*)(xlh + (size_t)i4 * 64 + c0);

        for (int j = 0; j < wavemax; j += 4) {
            bool a1 = j < deg, a2 = j + 1 < deg, a3 = j + 2 < deg, a4b = j + 3 < deg;
            half4v h1 = p1, h2 = p2, h3 = p3, h4x = p4;
            int n1 = (j + 4 < deg) ? tags[base + j + 4] : n;
            int n2 = (j + 5 < deg) ? tags[base + j + 5] : n;
            int n3 = (j + 6 < deg) ? tags[base + j + 6] : n;
            int n4 = (j + 7 < deg) ? tags[base + j + 7] : n;
            p1 = *(const half4v*)(xlh + (size_t)n1 * 64 + c0);
            p2 = *(const half4v*)(xlh + (size_t)n2 * 64 + c0);
            p3 = *(const half4v*)(xlh + (size_t)n3 * 64 + c0);
            p4 = *(const half4v*)(xlh + (size_t)n4 * 64 + c0);

            float e1 = edot(h1, xlo, xhi, alo, ahi, c02);
            float e2 = edot(h2, xlo, xhi, alo, ahi, c02);
            float e3 = edot(h3, xlo, xhi, alo, ahi, c02);
            float e4 = edot(h4x, xlo, xhi, alo, ahi, c02);
            e1 += __shfl_xor(e1, 1, 8); e2 += __shfl_xor(e2, 1, 8);
            e3 += __shfl_xor(e3, 1, 8); e4 += __shfl_xor(e4, 1, 8);
            e1 += __shfl_xor(e1, 2, 8); e2 += __shfl_xor(e2, 2, 8);
            e3 += __shfl_xor(e3, 2, 8); e4 += __shfl_xor(e4, 2, 8);
            e1 += __shfl_xor(e1, 4, 8); e2 += __shfl_xor(e2, 4, 8);
            e3 += __shfl_xor(e3, 4, 8); e4 += __shfl_xor(e4, 4, 8);
            if (!a1) e1 = -1e30f;
            if (!a2) e2 = -1e30f;
            if (!a3) e3 = -1e30f;
            if (!a4b) e4 = -1e30f;

            float mn = fmaxf(fmaxf(m, fmaxf(e1, e2)), fmaxf(e3, e4));
            float sc  = __expf(m - mn);
            float ex1 = __expf(e1 - mn);
            float ex2 = __expf(e2 - mn);
            float ex3 = __expf(e3 - mn);
            float ex4 = __expf(e4 - mn);
            den = den * sc + ((ex1 + ex2) + (ex3 + ex4));
            ac0 = fmaf(ex4, (float)h4x.x, fmaf(ex3, (float)h3.x,
                  fmaf(ex2, (float)h2.x, fmaf(ex1, (float)h1.x, ac0 * sc))));
            ac1 = fmaf(ex4, (float)h4x.y, fmaf(ex3, (float)h3.y,
                  fmaf(ex2, (float)h2.y, fmaf(ex1, (float)h1.y, ac1 * sc))));
            ac2 = fmaf(ex4, (float)h4x.z, fmaf(ex3, (float)h3.z,
                  fmaf(ex2, (float)h2.z, fmaf(ex1, (float)h1.z, ac2 * sc))));
            ac3 = fmaf(ex4, (float)h4x.w, fmaf(ex3, (float)h3.w,
                  fmaf(ex2, (float)h2.w, fmaf(ex1, (float)h1.w, ac3 * sc))));
            m = mn;
        }

        float inv = 1.f / den;
        half4v rh = *(const half4v*)(res16 + (size_t)n * 64 + c0);
        float h0, h1, h2, h3;
        if (bias) {
            const float4 b4 = *(const float4*)(bias + c0);
            h0 = relu(ac0 * inv + b4.x) + (float)rh.x;
            h1 = relu(ac1 * inv + b4.y) + (float)rh.y;
            h2 = relu(ac2 * inv + b4.z) + (float)rh.z;
            h3 = relu(ac3 * inv + b4.w) + (float)rh.w;
        } else {
            h0 = relu(ac0 * inv) + (float)rh.x;
            h1 = relu(ac1 * inv) + (float)rh.y;
            h2 = relu(ac2 * inv) + (float)rh.z;
            h3 = relu(ac3 * inv) + (float)rh.w;
        }

        if constexpr (LAYER == 0) {
            half4v o;
            o.x = (_Float16)h0; o.y = (_Float16)h1;
            o.z = (_Float16)h2; o.w = (_Float16)h3;
            h4[dlow][q] = o;
        } else {
            float p0 = h0 * wcomb[(c0 + 0) * 2] + h1 * wcomb[(c0 + 1) * 2]
                     + h2 * wcomb[(c0 + 2) * 2] + h3 * wcomb[(c0 + 3) * 2];
            float p1d = h0 * wcomb[(c0 + 0) * 2 + 1] + h1 * wcomb[(c0 + 1) * 2 + 1]
                      + h2 * wcomb[(c0 + 2) * 2 + 1] + h3 * wcomb[(c0 + 3) * 2 + 1];
            if (q < 4) {
                float4 c4 = *(const float4*)(cond + (size_t)n * 16 + q * 4);
                int d0 = 80 + q * 4;
                p0 += c4.x * wcomb[(d0 + 0) * 2] + c4.y * wcomb[(d0 + 1) * 2]
                    + c4.z * wcomb[(d0 + 2) * 2] + c4.w * wcomb[(d0 + 3) * 2];
                p1d += c4.x * wcomb[(d0 + 0) * 2 + 1] + c4.y * wcomb[(d0 + 1) * 2 + 1]
                     + c4.z * wcomb[(d0 + 2) * 2 + 1] + c4.w * wcomb[(d0 + 3) * 2 + 1];
            }
            #pragma unroll
            for (int off = 1; off < 16; off <<= 1) {
                p0 += __shfl_xor(p0, off, 16);
                p1d += __shfl_xor(p1d, off, 16);
            }
            if (q == 0 && nvalid) {
                out[(size_t)n * 2] = p0 + bfinal[0];
                out[(size_t)n * 2 + 1] = p1d + bfinal[1];
            }
        }
    }

    // ---- epilogue (L0): layer-1 precompute GEMM, W from global fp16 table ----
    if constexpr (LAYER == 0) {
        __syncthreads();
        int c = tid & 63, ww = tid >> 6;
        float al[8], ar[8], as2[8];
        float vbs = bres1[c];
        #pragma unroll
        for (int i = 0; i < 8; ++i) { al[i] = 0.f; ar[i] = 0.f; as2[i] = vbs; }

        #pragma unroll 4
        for (int k4 = 0; k4 < 16; ++k4) {
            half4v wl = w16[k4 * 64 + c];              // m=0
            half4v wr = w16[1024 + k4 * 64 + c];       // m=1
            half4v wsv = w16[2048 + k4 * 64 + c];      // m=2
            half2v wll = { wl.x, wl.y },  wlh = { wl.z, wl.w };
            half2v wrl = { wr.x, wr.y },  wrh = { wr.z, wr.w };
            half2v wsl = { wsv.x, wsv.y }, wsh = { wsv.z, wsv.w };
            #pragma unroll
            for (int i = 0; i < 8; ++i) {
                half4v hv = h4[ww * 8 + i][k4];   // same-addr broadcast
                half2v hl = { hv.x, hv.y }, hh = { hv.z, hv.w };
                al[i] = FDOT2(hl, wll, al[i]);
                al[i] = FDOT2(hh, wlh, al[i]);
                ar[i] = FDOT2(hl, wrl, ar[i]);
                ar[i] = FDOT2(hh, wrh, ar[i]);
                as2[i] = FDOT2(hl, wsl, as2[i]);
                as2[i] = FDOT2(hh, wsh, as2[i]);
            }
        }
        #pragma unroll
        for (int i = 0; i < 8; ++i) {
            int n = nb + ww * 8 + i;
            if (n < N) {
                xlh_out[(size_t)n * 64 + c] = (_Float16)al[i];
                xr_out[(size_t)n * 64 + c]  = (_Float16)ar[i];
                res_out[(size_t)n * 64 + c] = (_Float16)relu(as2[i]);
            }
        }
    }
}

static inline int gblk(long long threads) { return (int)((threads + BLK - 1) / BLK); }

extern "C" void kernel_launch(void* const* d_in, const int* in_sizes, int n_in,
                              void* d_out, int out_size, void* d_ws, size_t ws_size,
                              hipStream_t stream) {
    const float* x     = (const float*)d_in[0];
    const int*   ei    = (const int*)d_in[1];
    const int*   t     = (const int*)d_in[2];
    const float* cond  = (const float*)d_in[3];
    const float* Wl0   = (const float*)d_in[4];
    const float* bl0   = (const float*)d_in[5];
    const float* Wr0   = (const float*)d_in[6];
    const float* br0   = (const float*)d_in[7];
    const float* att0  = (const float*)d_in[8];
    const float* bias0 = (const float*)d_in[9];
    const float* Wres0 = (const float*)d_in[10];
    const float* bres0 = (const float*)d_in[11];
    const float* Wl1   = (const float*)d_in[12];
    const float* Wr1   = (const float*)d_in[13];
    const float* att1  = (const float*)d_in[14];
    const float* Wres1 = (const float*)d_in[15];
    const float* bres1 = (const float*)d_in[16];
    const float* Wt0   = (const float*)d_in[17];
    const float* bt0   = (const float*)d_in[18];
    const float* Wt1   = (const float*)d_in[19];
    const float* bt1   = (const float*)d_in[20];
    const float* Wfd   = (const float*)d_in[21];
    const float* bfd   = (const float*)d_in[22];
    const float* Wcls  = (const float*)d_in[23];
    const float* bcls  = (const float*)d_in[24];
    float* out = (float*)d_out;

    const int N   = in_sizes[0] / 16;
    const int E   = in_sizes[1] / 2;
    const int NBC = (N + CDST - 1) / CDST;
    const int NBF = (N + BDST - 1) / BDST;

    float* ws = (float*)d_ws;
    size_t o = 0;
    _Float16* xlhA  = (_Float16*)(ws + o); o += (size_t)N * 32;   // layer-0 xl
    _Float16* xlhB  = (_Float16*)(ws + o); o += (size_t)N * 32;   // layer-1 xl
    _Float16* xr16  = (_Float16*)(ws + o); o += (size_t)N * 32;
    _Float16* res16 = (_Float16*)(ws + o); o += (size_t)N * 32;
    half4v* w16  = (half4v*)(ws + o); o += 3 * 1024 * 2;          // 24KB fp16 W1
    float* wcomb = ws + o; o += 192;
    float* bfin  = ws + o; o += 2;
    int* iws     = (int*)(ws + o);
    size_t io = 0;
    int* ccnt    = iws + io; io += NBC_MAX;
    int* cbase   = iws + io; io += NBC_MAX + 1;
    int* ccur    = iws + io; io += NBC_MAX;
    int* donecnt = iws + io; io += 1;
    int* rowptr  = iws + io; io += (size_t)N + 1;
    int* part    = iws + io; io += E;
    int* srcs    = iws + io; io += E;

    const int partBlocks = (E + CHUNK - 1) / CHUNK;

    // tiny precompute (+ counters zero + W1 fp16 convert)
    k_tiny<<<1, BLK, 0, stream>>>(t, Wt0, bt0, Wt1, bt1, Wfd, bfd, Wcls, bcls,
                                  Wl1, Wr1, Wres1, wcomb, bfin, w16, ccnt, donecnt, NBC);

    // ---- radix partition by destination (histc has fused scan) ----
    k_histc<<<partBlocks, BLK, 0, stream>>>(ei, E, NBC, ccnt, donecnt, cbase, ccur, partBlocks);
    k_part<<<partBlocks, BLK, 0, stream>>>(ei, E, NBC, ccur, part);
    k_refine<<<NBC, BLK, 0, stream>>>(cbase, part, N, rowptr, srcs);

    // ---- layer 0 precompute ----
    k_pre0f<<<gblk((long long)((N + 3) / 4) * 64), BLK, 0, stream>>>(
        x, Wl0, bl0, Wr0, br0, Wres0, bres0, xlhA, xr16, res16, N);

    // ---- layer 0 GAT + fused layer-1 precompute ----
    k_gat3<0><<<NBF, BLK, 0, stream>>>(rowptr, srcs, xlhA, xr16, att0, bias0, res16,
                                       w16, bres1, xlhB, xr16, res16,
                                       nullptr, nullptr, nullptr, nullptr, N);

    // ---- layer 1 GAT + fused decoder ----
    k_gat3<1><<<NBF, BLK, 0, stream>>>(rowptr, srcs, xlhB, xr16, att1, nullptr, res16,
                                       nullptr, nullptr, nullptr, nullptr, nullptr,
                                       cond, wcomb, bfin, out, N);
}

// Round 16
// 271.163 us; speedup vs baseline: 1.0449x; 1.0449x over previous
//
#include <hip/hip_runtime.h>
#include <hip/hip_bf16.h>
#include <hip/hip_fp16.h>
#include <math.h>

// Edge_Encoder_Residual: 2-layer GATv2 on line-graph + time-MLP + decoder.
// Round 16: REVERT to r14 (best verified: 274.7us). r15's cleanup (exact
// sort in refine + fused scan) regressed +9us: bank-conflict elimination
// (399K->25K) gave zero speedup (conflicts were hidden under gather
// latency) while refine's serial 256-bin scan and per-block rowptr loads
// cost real time. Structure: radix partition -> pre0f (fp16 tables) ->
// gat3<0> (degree-ranked packed-fp16 4-batch edge loop + fused layer-1
// precompute GEMM via global fp16 W table) -> gat3<1> (+ fused decoder).

#define BLK 256
#define BDST 32            // dsts per fine bucket
#define CDST 256           // dsts per coarse bucket
#define CHUNK 4096         // edges per k_part block
#define FCAP 768           // tag capacity per fine bucket (mean 512)
#define NBC_MAX 512

typedef _Float16 half4v __attribute__((ext_vector_type(4)));
typedef _Float16 half2v __attribute__((ext_vector_type(2)));

#if __has_builtin(__builtin_amdgcn_fdot2)
#define FDOT2(a, b, c) __builtin_amdgcn_fdot2((a), (b), (c), false)
#else
__device__ __forceinline__ float fdot2_fallback(half2v a, half2v b, float c) {
    return c + (float)a.x * (float)b.x + (float)a.y * (float)b.y;
}
#define FDOT2(a, b, c) fdot2_fallback((a), (b), (c))
#endif

__device__ __forceinline__ float relu(float x) { return x > 0.f ? x : 0.f; }

// packed logit partial: sum_c leaky(h[c]+xr[c])*att[c] over this lane's 4 ch
__device__ __forceinline__ float edot(half4v h, half2v xlo, half2v xhi,
                                      half2v alo, half2v ahi, half2v c02) {
    half2v lo = half2v{h.x, h.y} + xlo;
    half2v hi = half2v{h.z, h.w} + xhi;
    lo = __builtin_elementwise_max(lo, lo * c02);
    hi = __builtin_elementwise_max(hi, hi * c02);
    return FDOT2(lo, alo, FDOT2(hi, ahi, 0.f));
}

// ---------- tiny: time-MLP + decoder collapse + ccnt zero + W1 fp16 convert --
__global__ void k_tiny(const int* __restrict__ t,
                       const float* __restrict__ Wt0, const float* __restrict__ bt0,
                       const float* __restrict__ Wt1, const float* __restrict__ bt1,
                       const float* __restrict__ Wfd, const float* __restrict__ bfd,
                       const float* __restrict__ Wcls, const float* __restrict__ bcls,
                       const float* __restrict__ Wl1, const float* __restrict__ Wr1,
                       const float* __restrict__ Wres1,
                       float* __restrict__ wcomb,   // [96][2]
                       float* __restrict__ bfinal,  // [2]
                       half4v* __restrict__ w16,    // [3][16][64] half4 (k-quads)
                       int* __restrict__ ccnt, int NBC)
{
    __shared__ float temb[16];
    int tid = threadIdx.x;
    // zero coarse counters
    for (int i = tid; i < NBC; i += BLK) ccnt[i] = 0;
    // convert W1 trio to fp16 half4 k-quad layout
    for (int idx = tid; idx < 3 * 1024; idx += BLK) {
        int m = idx >> 10, rem = idx & 1023;
        int k4 = rem >> 6, c = rem & 63;
        const float* W = (m == 0) ? Wl1 : (m == 1) ? Wr1 : Wres1;
        half4v v;
        v.x = (_Float16)W[(4 * k4 + 0) * 64 + c];
        v.y = (_Float16)W[(4 * k4 + 1) * 64 + c];
        v.z = (_Float16)W[(4 * k4 + 2) * 64 + c];
        v.w = (_Float16)W[(4 * k4 + 3) * 64 + c];
        w16[idx] = v;
    }
    if (tid == 0) {
        float tf = (float)t[0];
        float e0[16], v1[16];
        const float cexp = -logf(10000.f) / 7.f;
        for (int j = 0; j < 8; ++j) {
            float ang = tf * expf((float)j * cexp);
            e0[j] = sinf(ang);
            e0[8 + j] = cosf(ang);
        }
        for (int i = 0; i < 16; ++i) {
            float a = bt0[i];
            for (int j = 0; j < 16; ++j) a += e0[j] * Wt0[j * 16 + i];
            v1[i] = a / (1.f + expf(-a));
        }
        for (int i = 0; i < 16; ++i) {
            float a = bt1[i];
            for (int j = 0; j < 16; ++j) a += v1[j] * Wt1[j * 16 + i];
            temb[i] = a / (1.f + expf(-a));
        }
    }
    __syncthreads();
    if (tid < 192) {
        int i = tid >> 1, k = tid & 1;
        float a = 0.f;
        for (int j = 0; j < 32; ++j) a += Wfd[i * 32 + j] * Wcls[j * 2 + k];
        wcomb[tid] = a;
    }
    __syncthreads();
    if (tid < 2) {
        float a = bcls[tid];
        for (int j = 0; j < 32; ++j) a += bfd[j] * Wcls[j * 2 + tid];
        for (int d = 0; d < 16; ++d) a += temb[d] * wcomb[(64 + d) * 2 + tid];
        bfinal[tid] = a;
    }
}

// ---------- radix pipeline ----------
__global__ void k_histc(const int* __restrict__ ei, int E, int NBC,
                        int* __restrict__ ccnt)
{
    __shared__ int h[NBC_MAX];
    int tid = threadIdx.x;
    for (int i = tid; i < NBC; i += BLK) h[i] = 0;
    __syncthreads();
    int e0 = blockIdx.x * CHUNK;
    #pragma unroll
    for (int k = 0; k < CHUNK / BLK; ++k) {
        int e = e0 + tid + k * BLK;
        if (e < E) atomicAdd(&h[ei[E + e] >> 8], 1);
    }
    __syncthreads();
    for (int i = tid; i < NBC; i += BLK) {
        int v = h[i];
        if (v) atomicAdd(&ccnt[i], v);   // fire-and-forget -> pipelines
    }
}

__global__ void k_scan(const int* __restrict__ ccnt, int NBC, int E,
                       int* __restrict__ cbase, int* __restrict__ ccur)
{
    if (threadIdx.x == 0) {
        int acc = 0;
        for (int i = 0; i < NBC; ++i) {
            cbase[i] = acc;
            acc += ccnt[i];
        }
        cbase[NBC] = acc;
    }
    __syncthreads();
    for (int i = threadIdx.x; i < NBC; i += BLK) ccur[i] = cbase[i];
}

__global__ void k_part(const int* __restrict__ ei, int E, int NBC,
                       int* __restrict__ ccur, int* __restrict__ part)
{
    __shared__ int h[NBC_MAX];
    __shared__ int gb[NBC_MAX];
    int tid = threadIdx.x;
    int e0 = blockIdx.x * CHUNK;
    for (int i = tid; i < NBC; i += BLK) h[i] = 0;
    __syncthreads();
    int sv[CHUNK / BLK], dv[CHUNK / BLK];
    #pragma unroll
    for (int k = 0; k < CHUNK / BLK; ++k) {
        int e = e0 + tid + k * BLK;
        if (e < E) {
            sv[k] = ei[e];
            dv[k] = ei[E + e];
            atomicAdd(&h[dv[k] >> 8], 1);
        } else dv[k] = -1;
    }
    __syncthreads();
    for (int i = tid; i < NBC; i += BLK) {
        int v = h[i];
        gb[i] = v ? atomicAdd(&ccur[i], v) : 0;   // block-agg returning atomics
    }
    __syncthreads();
    for (int i = tid; i < NBC; i += BLK) h[i] = gb[i];
    __syncthreads();
    #pragma unroll
    for (int k = 0; k < CHUNK / BLK; ++k) {
        if (dv[k] >= 0) {
            int p = atomicAdd(&h[dv[k] >> 8], 1);   // LDS atomic
            part[p] = (sv[k] << 8) | (dv[k] & 255);
        }
    }
}

__global__ void k_refine(const int* __restrict__ cbase, const int* __restrict__ part,
                         int NBF, int* __restrict__ fbeg, int* __restrict__ fend,
                         int* __restrict__ srcs)
{
    __shared__ int fcnt[8];
    __shared__ int fcur[8];
    int b = blockIdx.x, tid = threadIdx.x;
    int beg = cbase[b], end = cbase[b + 1];
    if (tid < 8) fcnt[tid] = 0;
    __syncthreads();
    for (int k = beg + tid; k < end; k += BLK)
        atomicAdd(&fcnt[(part[k] >> 5) & 7], 1);
    __syncthreads();
    if (tid == 0) {
        int acc = beg;
        #pragma unroll
        for (int f = 0; f < 8; ++f) {
            int fb = b * 8 + f;
            fcur[f] = acc;
            if (fb < NBF) { fbeg[fb] = acc; acc += fcnt[f]; fend[fb] = acc; }
        }
    }
    __syncthreads();
    for (int k = beg + tid; k < end; k += BLK) {
        int tg = part[k];
        int p = atomicAdd(&fcur[(tg >> 5) & 7], 1);
        srcs[p] = ((tg >> 8) << 5) | (tg & 31);
    }
}

// ---------- layer 0 precompute: xl, xr, res — all fp16, 4 nodes/wave ----------
__global__ void k_pre0f(const float* __restrict__ x,
                        const float* __restrict__ Wl, const float* __restrict__ bl,
                        const float* __restrict__ Wr, const float* __restrict__ br,
                        const float* __restrict__ Wres, const float* __restrict__ bres,
                        _Float16* __restrict__ xlh, _Float16* __restrict__ xr16,
                        _Float16* __restrict__ res16, int N)
{
    int wid = (int)(((long long)blockIdx.x * BLK + threadIdx.x) >> 6);
    int lane = threadIdx.x & 63;
    int g = lane >> 4, q = lane & 15;
    int n = wid * 4 + g;
    bool valid = n < N;
    int nn = valid ? n : N - 1;
    float xv = x[(size_t)nn * 16 + q];
    int c0 = q * 4;
    float4 accl = *(const float4*)(bl + c0);
    float4 accr = *(const float4*)(br + c0);
    float4 accs = *(const float4*)(bres + c0);
    #pragma unroll
    for (int k = 0; k < 16; ++k) {
        float xk = __shfl(xv, (g << 4) | k, 64);
        float4 wl = *(const float4*)(Wl + k * 64 + c0);
        float4 wr = *(const float4*)(Wr + k * 64 + c0);
        float4 wsv = *(const float4*)(Wres + k * 64 + c0);
        accl.x = fmaf(xk, wl.x, accl.x);
        accl.y = fmaf(xk, wl.y, accl.y);
        accl.z = fmaf(xk, wl.z, accl.z);
        accl.w = fmaf(xk, wl.w, accl.w);
        accr.x = fmaf(xk, wr.x, accr.x);
        accr.y = fmaf(xk, wr.y, accr.y);
        accr.z = fmaf(xk, wr.z, accr.z);
        accr.w = fmaf(xk, wr.w, accr.w);
        accs.x = fmaf(xk, wsv.x, accs.x);
        accs.y = fmaf(xk, wsv.y, accs.y);
        accs.z = fmaf(xk, wsv.z, accs.z);
        accs.w = fmaf(xk, wsv.w, accs.w);
    }
    if (valid) {
        size_t base = (size_t)n * 64 + c0;
        half4v hl, hr, hs;
        hl.x = (_Float16)accl.x; hl.y = (_Float16)accl.y;
        hl.z = (_Float16)accl.z; hl.w = (_Float16)accl.w;
        hr.x = (_Float16)accr.x; hr.y = (_Float16)accr.y;
        hr.z = (_Float16)accr.z; hr.w = (_Float16)accr.w;
        hs.x = (_Float16)relu(accs.x); hs.y = (_Float16)relu(accs.y);
        hs.z = (_Float16)relu(accs.z); hs.w = (_Float16)relu(accs.w);
        *(half4v*)(xlh + base) = hl;
        *(half4v*)(xr16 + base) = hr;
        *(half4v*)(res16 + base) = hs;
    }
}

// ---------- fused GATv2 (+ layer-1 precompute GEMM for LAYER==0) ----------
// LAYER==0: r12 edge loop -> h stash in LDS (4KB) -> fdot2 GEMM epilogue
//           reading W from global fp16 table w16 (L2-resident).
// LAYER==1: r12 edge loop -> fused decoder.
template <int LAYER>
__global__ void k_gat3(const int* __restrict__ fbeg, const int* __restrict__ fend,
                       const int* __restrict__ srcs,
                       const _Float16* __restrict__ xlh, const _Float16* __restrict__ xr16,
                       const float* __restrict__ att, const float* __restrict__ bias,
                       const _Float16* __restrict__ res16,
                       const half4v* __restrict__ w16, const float* __restrict__ bres1,
                       _Float16* __restrict__ xlh_out, _Float16* __restrict__ xr_out,
                       _Float16* __restrict__ res_out,
                       const float* __restrict__ cond, const float* __restrict__ wcomb,
                       const float* __restrict__ bfinal, float* __restrict__ out,
                       int N)
{
    __shared__ int lh[BDST];
    __shared__ int rp[BDST + 1];
    __shared__ int cc[BDST];
    __shared__ int sidx[BDST];
    __shared__ int tags[FCAP];
    __shared__ half4v h4[LAYER == 0 ? 32 : 1][16];   // h stash (4KB, L0 only)

    int b = blockIdx.x;
    int tid = threadIdx.x;
    int beg = fbeg[b];
    int nE = fend[b] - beg; if (nE > FCAP) nE = FCAP;

    if (tid < BDST) lh[tid] = 0;
    __syncthreads();
    for (int k = tid; k < nE; k += BLK) atomicAdd(&lh[srcs[beg + k] & 31], 1);
    __syncthreads();
    if (tid == 0) {
        int acc = 0;
        rp[0] = 0;
        #pragma unroll
        for (int i = 0; i < BDST; ++i) { acc += lh[i]; rp[i + 1] = acc; }
    }
    __syncthreads();
    if (tid < BDST) cc[tid] = rp[tid];
    __syncthreads();
    for (int k = tid; k < nE; k += BLK) {
        int tg = srcs[beg + k];
        int r = atomicAdd(&cc[tg & 31], 1);
        tags[r] = tg >> 5;
    }
    // degree-rank: sidx[rank] = dlow, descending degree (ties by index)
    if (tid < BDST) {
        int di = rp[tid + 1] - rp[tid];
        int r = 0;
        #pragma unroll
        for (int j = 0; j < BDST; ++j) {
            int dj = rp[j + 1] - rp[j];
            r += (dj > di) || (dj == di && j < tid);
        }
        sidx[r] = tid;
    }
    __syncthreads();

    int lane = tid & 63, w = tid >> 6;
    int g = lane >> 4, q = lane & 15;
    int c0 = q * 4;
    float4 a4f = *(const float4*)(att + c0);
    const half2v c02 = { (_Float16)0.2f, (_Float16)0.2f };
    half2v alo = { (_Float16)a4f.x, (_Float16)a4f.y };
    half2v ahi = { (_Float16)a4f.z, (_Float16)a4f.w };

    #pragma unroll
    for (int rep = 0; rep < 2; ++rep) {
        int dlow = sidx[w * 8 + rep * 4 + g];   // similar-degree group
        int node = b * BDST + dlow;
        bool nvalid = node < N;
        int n = nvalid ? node : 0;

        half4v xrh = *(const half4v*)(xr16 + (size_t)n * 64 + c0);
        half2v xlo = { xrh.x, xrh.y }, xhi = { xrh.z, xrh.w };

        half4v hsv = *(const half4v*)(xlh + (size_t)n * 64 + c0);
        float lv = edot(hsv, xlo, xhi, alo, ahi, c02);
        lv += __shfl_xor(lv, 1, 8);
        lv += __shfl_xor(lv, 2, 8);
        lv += __shfl_xor(lv, 4, 8);

        float m = lv, den = 1.f;
        float ac0 = (float)hsv.x, ac1 = (float)hsv.y;
        float ac2 = (float)hsv.z, ac3 = (float)hsv.w;

        int deg = nvalid ? (rp[dlow + 1] - rp[dlow]) : 0;
        int base = nvalid ? rp[dlow] : 0;

        int t1 = max(deg, __shfl_xor(deg, 16, 64));
        int wavemax = max(t1, __shfl_xor(t1, 32, 64));

        // 4-deep prefetch
        int i1 = (0 < deg) ? tags[base + 0] : n;
        int i2 = (1 < deg) ? tags[base + 1] : n;
        int i3 = (2 < deg) ? tags[base + 2] : n;
        int i4 = (3 < deg) ? tags[base + 3] : n;
        half4v p1 = *(const half4v*)(xlh + (size_t)i1 * 64 + c0);
        half4v p2 = *(const half4v*)(xlh + (size_t)i2 * 64 + c0);
        half4v p3 = *(const half4v*)(xlh + (size_t)i3 * 64 + c0);
        half4v p4 = *(const half4v*)(xlh + (size_t)i4 * 64 + c0);

        for (int j = 0; j < wavemax; j += 4) {
            bool a1 = j < deg, a2 = j + 1 < deg, a3 = j + 2 < deg, a4b = j + 3 < deg;
            half4v h1 = p1, h2 = p2, h3 = p3, h4x = p4;
            int n1 = (j + 4 < deg) ? tags[base + j + 4] : n;
            int n2 = (j + 5 < deg) ? tags[base + j + 5] : n;
            int n3 = (j + 6 < deg) ? tags[base + j + 6] : n;
            int n4 = (j + 7 < deg) ? tags[base + j + 7] : n;
            p1 = *(const half4v*)(xlh + (size_t)n1 * 64 + c0);
            p2 = *(const half4v*)(xlh + (size_t)n2 * 64 + c0);
            p3 = *(const half4v*)(xlh + (size_t)n3 * 64 + c0);
            p4 = *(const half4v*)(xlh + (size_t)n4 * 64 + c0);

            float e1 = edot(h1, xlo, xhi, alo, ahi, c02);
            float e2 = edot(h2, xlo, xhi, alo, ahi, c02);
            float e3 = edot(h3, xlo, xhi, alo, ahi, c02);
            float e4 = edot(h4x, xlo, xhi, alo, ahi, c02);
            e1 += __shfl_xor(e1, 1, 8); e2 += __shfl_xor(e2, 1, 8);
            e3 += __shfl_xor(e3, 1, 8); e4 += __shfl_xor(e4, 1, 8);
            e1 += __shfl_xor(e1, 2, 8); e2 += __shfl_xor(e2, 2, 8);
            e3 += __shfl_xor(e3, 2, 8); e4 += __shfl_xor(e4, 2, 8);
            e1 += __shfl_xor(e1, 4, 8); e2 += __shfl_xor(e2, 4, 8);
            e3 += __shfl_xor(e3, 4, 8); e4 += __shfl_xor(e4, 4, 8);
            if (!a1) e1 = -1e30f;
            if (!a2) e2 = -1e30f;
            if (!a3) e3 = -1e30f;
            if (!a4b) e4 = -1e30f;

            float mn = fmaxf(fmaxf(m, fmaxf(e1, e2)), fmaxf(e3, e4));
            float sc  = __expf(m - mn);
            float ex1 = __expf(e1 - mn);
            float ex2 = __expf(e2 - mn);
            float ex3 = __expf(e3 - mn);
            float ex4 = __expf(e4 - mn);
            den = den * sc + ((ex1 + ex2) + (ex3 + ex4));
            ac0 = fmaf(ex4, (float)h4x.x, fmaf(ex3, (float)h3.x,
                  fmaf(ex2, (float)h2.x, fmaf(ex1, (float)h1.x, ac0 * sc))));
            ac1 = fmaf(ex4, (float)h4x.y, fmaf(ex3, (float)h3.y,
                  fmaf(ex2, (float)h2.y, fmaf(ex1, (float)h1.y, ac1 * sc))));
            ac2 = fmaf(ex4, (float)h4x.z, fmaf(ex3, (float)h3.z,
                  fmaf(ex2, (float)h2.z, fmaf(ex1, (float)h1.z, ac2 * sc))));
            ac3 = fmaf(ex4, (float)h4x.w, fmaf(ex3, (float)h3.w,
                  fmaf(ex2, (float)h2.w, fmaf(ex1, (float)h1.w, ac3 * sc))));
            m = mn;
        }

        float inv = 1.f / den;
        half4v rh = *(const half4v*)(res16 + (size_t)n * 64 + c0);
        float h0, h1, h2, h3;
        if (bias) {
            const float4 b4 = *(const float4*)(bias + c0);
            h0 = relu(ac0 * inv + b4.x) + (float)rh.x;
            h1 = relu(ac1 * inv + b4.y) + (float)rh.y;
            h2 = relu(ac2 * inv + b4.z) + (float)rh.z;
            h3 = relu(ac3 * inv + b4.w) + (float)rh.w;
        } else {
            h0 = relu(ac0 * inv) + (float)rh.x;
            h1 = relu(ac1 * inv) + (float)rh.y;
            h2 = relu(ac2 * inv) + (float)rh.z;
            h3 = relu(ac3 * inv) + (float)rh.w;
        }

        if constexpr (LAYER == 0) {
            half4v o;
            o.x = (_Float16)h0; o.y = (_Float16)h1;
            o.z = (_Float16)h2; o.w = (_Float16)h3;
            h4[dlow][q] = o;
        } else {
            float p0 = h0 * wcomb[(c0 + 0) * 2] + h1 * wcomb[(c0 + 1) * 2]
                     + h2 * wcomb[(c0 + 2) * 2] + h3 * wcomb[(c0 + 3) * 2];
            float p1d = h0 * wcomb[(c0 + 0) * 2 + 1] + h1 * wcomb[(c0 + 1) * 2 + 1]
                      + h2 * wcomb[(c0 + 2) * 2 + 1] + h3 * wcomb[(c0 + 3) * 2 + 1];
            if (q < 4) {
                float4 c4 = *(const float4*)(cond + (size_t)n * 16 + q * 4);
                int d0 = 80 + q * 4;
                p0 += c4.x * wcomb[(d0 + 0) * 2] + c4.y * wcomb[(d0 + 1) * 2]
                    + c4.z * wcomb[(d0 + 2) * 2] + c4.w * wcomb[(d0 + 3) * 2];
                p1d += c4.x * wcomb[(d0 + 0) * 2 + 1] + c4.y * wcomb[(d0 + 1) * 2 + 1]
                     + c4.z * wcomb[(d0 + 2) * 2 + 1] + c4.w * wcomb[(d0 + 3) * 2 + 1];
            }
            #pragma unroll
            for (int off = 1; off < 16; off <<= 1) {
                p0 += __shfl_xor(p0, off, 16);
                p1d += __shfl_xor(p1d, off, 16);
            }
            if (q == 0 && nvalid) {
                out[(size_t)n * 2] = p0 + bfinal[0];
                out[(size_t)n * 2 + 1] = p1d + bfinal[1];
            }
        }
    }

    // ---- epilogue (L0): layer-1 precompute GEMM, W from global fp16 table ----
    if constexpr (LAYER == 0) {
        __syncthreads();
        int nb = b * BDST;
        int c = tid & 63, ww = tid >> 6;
        float al[8], ar[8], as2[8];
        float vbs = bres1[c];
        #pragma unroll
        for (int i = 0; i < 8; ++i) { al[i] = 0.f; ar[i] = 0.f; as2[i] = vbs; }

        #pragma unroll 4
        for (int k4 = 0; k4 < 16; ++k4) {
            half4v wl = w16[k4 * 64 + c];              // m=0
            half4v wr = w16[1024 + k4 * 64 + c];       // m=1
            half4v wsv = w16[2048 + k4 * 64 + c];      // m=2
            half2v wll = { wl.x, wl.y },  wlh = { wl.z, wl.w };
            half2v wrl = { wr.x, wr.y },  wrh = { wr.z, wr.w };
            half2v wsl = { wsv.x, wsv.y }, wsh = { wsv.z, wsv.w };
            #pragma unroll
            for (int i = 0; i < 8; ++i) {
                half4v hv = h4[ww * 8 + i][k4];   // same-addr broadcast
                half2v hl = { hv.x, hv.y }, hh = { hv.z, hv.w };
                al[i] = FDOT2(hl, wll, al[i]);
                al[i] = FDOT2(hh, wlh, al[i]);
                ar[i] = FDOT2(hl, wrl, ar[i]);
                ar[i] = FDOT2(hh, wrh, ar[i]);
                as2[i] = FDOT2(hl, wsl, as2[i]);
                as2[i] = FDOT2(hh, wsh, as2[i]);
            }
        }
        #pragma unroll
        for (int i = 0; i < 8; ++i) {
            int n = nb + ww * 8 + i;
            if (n < N) {
                xlh_out[(size_t)n * 64 + c] = (_Float16)al[i];
                xr_out[(size_t)n * 64 + c]  = (_Float16)ar[i];
                res_out[(size_t)n * 64 + c] = (_Float16)relu(as2[i]);
            }
        }
    }
}

static inline int gblk(long long threads) { return (int)((threads + BLK - 1) / BLK); }

extern "C" void kernel_launch(void* const* d_in, const int* in_sizes, int n_in,
                              void* d_out, int out_size, void* d_ws, size_t ws_size,
                              hipStream_t stream) {
    const float* x     = (const float*)d_in[0];
    const int*   ei    = (const int*)d_in[1];
    const int*   t     = (const int*)d_in[2];
    const float* cond  = (const float*)d_in[3];
    const float* Wl0   = (const float*)d_in[4];
    const float* bl0   = (const float*)d_in[5];
    const float* Wr0   = (const float*)d_in[6];
    const float* br0   = (const float*)d_in[7];
    const float* att0  = (const float*)d_in[8];
    const float* bias0 = (const float*)d_in[9];
    const float* Wres0 = (const float*)d_in[10];
    const float* bres0 = (const float*)d_in[11];
    const float* Wl1   = (const float*)d_in[12];
    const float* Wr1   = (const float*)d_in[13];
    const float* att1  = (const float*)d_in[14];
    const float* Wres1 = (const float*)d_in[15];
    const float* bres1 = (const float*)d_in[16];
    const float* Wt0   = (const float*)d_in[17];
    const float* bt0   = (const float*)d_in[18];
    const float* Wt1   = (const float*)d_in[19];
    const float* bt1   = (const float*)d_in[20];
    const float* Wfd   = (const float*)d_in[21];
    const float* bfd   = (const float*)d_in[22];
    const float* Wcls  = (const float*)d_in[23];
    const float* bcls  = (const float*)d_in[24];
    float* out = (float*)d_out;

    const int N   = in_sizes[0] / 16;
    const int E   = in_sizes[1] / 2;
    const int NBC = (N + CDST - 1) / CDST;
    const int NBF = (N + BDST - 1) / BDST;

    float* ws = (float*)d_ws;
    size_t o = 0;
    _Float16* xlhA  = (_Float16*)(ws + o); o += (size_t)N * 32;   // layer-0 xl
    _Float16* xlhB  = (_Float16*)(ws + o); o += (size_t)N * 32;   // layer-1 xl
    _Float16* xr16  = (_Float16*)(ws + o); o += (size_t)N * 32;
    _Float16* res16 = (_Float16*)(ws + o); o += (size_t)N * 32;
    half4v* w16  = (half4v*)(ws + o); o += 3 * 1024 * 2;          // 24KB fp16 W1
    float* wcomb = ws + o; o += 192;
    float* bfin  = ws + o; o += 2;
    int* iws     = (int*)(ws + o);
    size_t io = 0;
    int* ccnt  = iws + io; io += NBC_MAX;
    int* cbase = iws + io; io += NBC_MAX + 1;
    int* ccur  = iws + io; io += NBC_MAX;
    int* fbeg  = iws + io; io += NBF;
    int* fend  = iws + io; io += NBF;
    int* part  = iws + io; io += E;
    int* srcs  = iws + io; io += E;

    const int partBlocks = (E + CHUNK - 1) / CHUNK;

    // tiny precompute (+ ccnt zero + W1 fp16 convert)
    k_tiny<<<1, BLK, 0, stream>>>(t, Wt0, bt0, Wt1, bt1, Wfd, bfd, Wcls, bcls,
                                  Wl1, Wr1, Wres1, wcomb, bfin, w16, ccnt, NBC);

    // ---- radix partition by destination ----
    k_histc<<<partBlocks, BLK, 0, stream>>>(ei, E, NBC, ccnt);
    k_scan<<<1, BLK, 0, stream>>>(ccnt, NBC, E, cbase, ccur);
    k_part<<<partBlocks, BLK, 0, stream>>>(ei, E, NBC, ccur, part);
    k_refine<<<NBC, BLK, 0, stream>>>(cbase, part, NBF, fbeg, fend, srcs);

    // ---- layer 0 precompute ----
    k_pre0f<<<gblk((long long)((N + 3) / 4) * 64), BLK, 0, stream>>>(
        x, Wl0, bl0, Wr0, br0, Wres0, bres0, xlhA, xr16, res16, N);

    // ---- layer 0 GAT + fused layer-1 precompute (low-LDS epilogue) ----
    k_gat3<0><<<NBF, BLK, 0, stream>>>(fbeg, fend, srcs, xlhA, xr16, att0, bias0, res16,
                                       w16, bres1, xlhB, xr16, res16,
                                       nullptr, nullptr, nullptr, nullptr, N);

    // ---- layer 1 GAT + fused decoder ----
    k_gat3<1><<<NBF, BLK, 0, stream>>>(fbeg, fend, srcs, xlhB, xr16, att1, nullptr, res16,
                                       nullptr, nullptr, nullptr, nullptr, nullptr,
                                       cond, wcomb, bfin, out, N);
}